// Round 5
// baseline (433.025 us; speedup 1.0000x reference)
//
#include <hip/hip_runtime.h>
#include <hip/hip_bf16.h>
#include <stdint.h>

// RNNPool on MI355X: B=16, S=4096, E=512, window=8.
// Round 5: latency-bound fix. rec_kernel restructured:
//   512 blocks x 512 thr (8 waves), 16 windows/block -> 2 blocks/CU, so one
//   block's waves cover the other's barrier stalls. h double-buffered in LDS
//   (bf16 hi+lo) -> ONE barrier per step. PRE nontemporal + reg prefetch.

#define E_DIM 512
#define KSIZE 8
#define R_WIN 32           // windows per pre-kernel block
#define NBLK  256

typedef __attribute__((ext_vector_type(8))) short          bf16x8;  // MFMA A/B frag
typedef __attribute__((ext_vector_type(4))) float          f32x4;   // MFMA C/D frag
typedef __attribute__((ext_vector_type(4))) float          fv4;
typedef __attribute__((ext_vector_type(4))) unsigned short u16x4;
typedef __attribute__((ext_vector_type(8))) unsigned short u16x8;

__device__ __forceinline__ unsigned short f2bf(float f) {
  union { float f; uint32_t u; } v; v.f = f;
  uint32_t u = v.u;
  uint32_t r = u + 0x7FFFu + ((u >> 16) & 1u);   // round-to-nearest-even
  return (unsigned short)(r >> 16);
}
__device__ __forceinline__ float bf2f(unsigned short h) {
  union { uint32_t u; float f; } v; v.u = ((uint32_t)h) << 16;
  return v.f;
}
__device__ __forceinline__ float tanh_fast(float v) {
  return 1.0f - 2.0f / (1.0f + __expf(2.0f * v));   // exact saturation, 1 v_exp
}
// LDS XOR-swizzle key (function of row only: write/read sides agree).
__device__ __forceinline__ int swz(int row) { return (row ^ (row >> 1)) & 7; }

// ---------------------------------------------------------------------------
// Pack W_ih / W_hh into bf16 fragment-major (mfma_f32_16x16x32_bf16 B-operand):
//   lane l holds W[n*16 + (l&15)][s*32 + (l>>4)*8 + j], ushort idx ((m*32+n)*16+s)*512 + l*8
// bias[n] = b_ih[n] + b_hh[n].
// ---------------------------------------------------------------------------
__global__ void pack_kernel(const float* __restrict__ Wih, const float* __restrict__ Whh,
                            const float* __restrict__ bih, const float* __restrict__ bhh,
                            unsigned short* __restrict__ wpack, float* __restrict__ bias) {
  int tid = blockIdx.x * 256 + threadIdx.x;          // 65536 threads total
  int l = tid & 63;
  int s = (tid >> 6) & 15;
  int n = (tid >> 10) & 31;
  int m = tid >> 15;
  const float* W = m ? Whh : Wih;
  int row = n * 16 + (l & 15);
  int k0  = s * 32 + (l >> 4) * 8;
  const float* src = W + row * E_DIM + k0;
  u16x8 u;
  #pragma unroll
  for (int j = 0; j < 8; ++j) u[j] = f2bf(src[j]);
  *reinterpret_cast<u16x8*>(wpack + (size_t)tid * 8) = u;
  if (tid < E_DIM) bias[tid] = bih[tid] + bhh[tid];
}

// PRE fragment layout: frag id = ((bt*2 + mt)*32 + nt), bt = bp*8+t, bp in [0,256)
// frag = 256 floats = 64 lanes x f32x4 (C/D: col=lane&15, row=(lane>>4)*4+r).
#define PRE_FRAG(bt, mt, nt) ((((size_t)(bt) * 2 + (mt)) * 32 + (nt)) * 256)

// ---------------------------------------------------------------------------
// Phase 1: PRE = x_t @ W_ih^T + bias. Grid 2048, 512 thr (8 waves x 4 N-tiles).
// x loads and PRE stores nontemporal so W_ih stays L2-resident.
// ---------------------------------------------------------------------------
__global__ __launch_bounds__(512, 4)
void pre_kernel(const float* __restrict__ x,
                const unsigned short* __restrict__ wpack,
                const float* __restrict__ bias,
                float* __restrict__ prep) {
  __shared__ unsigned short x_lds[R_WIN * E_DIM];   // 32 KB

  const int bt   = blockIdx.x;
  const int b    = bt >> 3;
  const int t    = bt & 7;
  const int w0   = b * R_WIN;
  const int tid  = threadIdx.x;
  const int lane = tid & 63;
  const int wid  = tid >> 6;          // 0..7
  const int l15  = lane & 15;
  const int a5   = lane >> 4;
  const int nt0  = wid * 4;

  float bias_r[4];
  #pragma unroll
  for (int n = 0; n < 4; ++n) bias_r[n] = bias[(nt0 + n) * 16 + l15];

  const unsigned short* wpI = wpack + nt0 * 8192 + lane * 8;

  // stage x (nontemporal: read-once stream; don't evict W_ih from L2)
  {
    const int srow = tid >> 4;
    const int sc4  = tid & 15;
    const fv4* src4 = reinterpret_cast<const fv4*>(
        x + (size_t)((w0 + srow) * KSIZE + t) * E_DIM);
    #pragma unroll
    for (int j = 0; j < 8; ++j) {
      fv4 v = __builtin_nontemporal_load(&src4[sc4 + 16 * j]);
      int col  = (sc4 + 16 * j) * 4;
      int idx  = srow * E_DIM + (((col >> 3) ^ swz(srow)) << 3) + (col & 7);
      u16x4 u;
      u[0] = f2bf(v.x); u[1] = f2bf(v.y); u[2] = f2bf(v.z); u[3] = f2bf(v.w);
      *reinterpret_cast<u16x4*>(&x_lds[idx]) = u;
    }
  }
  __syncthreads();

  f32x4 acc[2][4];
  #pragma unroll
  for (int mt = 0; mt < 2; ++mt)
    #pragma unroll
    for (int n = 0; n < 4; ++n) acc[mt][n] = (f32x4){0.f, 0.f, 0.f, 0.f};

  #pragma unroll
  for (int s = 0; s < 16; ++s) {
    int u0 = s * 4 + a5;
    int ia = l15 * E_DIM + ((u0 ^ swz(l15)) << 3);
    bf16x8 A0 = *reinterpret_cast<const bf16x8*>(&x_lds[ia]);
    bf16x8 A1 = *reinterpret_cast<const bf16x8*>(&x_lds[ia + 16 * E_DIM]);
    #pragma unroll
    for (int n = 0; n < 4; ++n) {
      bf16x8 Bf = *reinterpret_cast<const bf16x8*>(wpI + n * 8192 + s * 512);
      acc[0][n] = __builtin_amdgcn_mfma_f32_16x16x32_bf16(A0, Bf, acc[0][n], 0, 0, 0);
      acc[1][n] = __builtin_amdgcn_mfma_f32_16x16x32_bf16(A1, Bf, acc[1][n], 0, 0, 0);
    }
  }

  // store fragment-major, nontemporal (streams straight out, keeps L2 clean)
  #pragma unroll
  for (int mt = 0; mt < 2; ++mt)
    #pragma unroll
    for (int n = 0; n < 4; ++n) {
      f32x4 v = acc[mt][n];
      #pragma unroll
      for (int r = 0; r < 4; ++r) v[r] += bias_r[n];
      __builtin_nontemporal_store(v,
          reinterpret_cast<f32x4*>(&prep[PRE_FRAG(bt, mt, nt0 + n) + lane * 4]));
    }
}

// ---------------------------------------------------------------------------
// Phase 2: recurrence. Grid 512, 512 thr = 8 waves x 4 N-tiles; 16 windows
// per block; 2 blocks/CU (64 KB LDS each) so blocks cover each other's
// barrier stalls. h double-buffered -> ONE barrier per step.
// ---------------------------------------------------------------------------
__global__ __launch_bounds__(512, 4)
void rec_kernel(const float* __restrict__ prep,
                const unsigned short* __restrict__ wpack,
                float* __restrict__ out) {
  __shared__ unsigned short h_hi[2][16 * E_DIM];    // 32 KB
  __shared__ unsigned short h_lo[2][16 * E_DIM];    // 32 KB

  const int rb   = blockIdx.x;          // 0..511
  const int bp   = rb >> 1;             // matching pre_kernel block
  const int mt   = rb & 1;              // which 16-window half of that block
  const int w0   = rb * 16;
  const int tid  = threadIdx.x;
  const int lane = tid & 63;
  const int wid  = tid >> 6;            // 0..7
  const int l15  = lane & 15;
  const int a5   = lane >> 4;
  const int nt0  = wid * 4;

  const unsigned short* wpH = wpack + 262144 + nt0 * 8192 + lane * 8;

  // ---- t = 0: h[0] = tanh(PRE_0) ----
  #pragma unroll
  for (int n = 0; n < 4; ++n) {
    f32x4 p = __builtin_nontemporal_load(reinterpret_cast<const f32x4*>(
        &prep[PRE_FRAG(bp * 8 + 0, mt, nt0 + n) + lane * 4]));
    int ncol = (nt0 + n) * 16 + l15;
    int ub = ncol >> 3, co = ncol & 7;
    #pragma unroll
    for (int r = 0; r < 4; ++r) {
      int row = a5 * 4 + r;
      float th = tanh_fast(p[r]);
      unsigned short hi = f2bf(th);
      unsigned short lo = f2bf(th - bf2f(hi));
      int idx = row * E_DIM + ((ub ^ swz(row)) << 3) + co;
      h_hi[0][idx] = hi;
      h_lo[0][idx] = lo;
    }
  }

  // prefetch PRE_1 into registers
  f32x4 nxt[4];
  #pragma unroll
  for (int n = 0; n < 4; ++n)
    nxt[n] = __builtin_nontemporal_load(reinterpret_cast<const f32x4*>(
        &prep[PRE_FRAG(bp * 8 + 1, mt, nt0 + n) + lane * 4]));

  __syncthreads();   // h[0] visible

  int cur = 0;
  for (int t = 1; t < KSIZE; ++t) {
    f32x4 acc[4];
    #pragma unroll
    for (int n = 0; n < 4; ++n) acc[n] = nxt[n];

    // issue next step's PRE loads now: latency hides under MFMA phase (T14)
    if (t + 1 < KSIZE) {
      #pragma unroll
      for (int n = 0; n < 4; ++n)
        nxt[n] = __builtin_nontemporal_load(reinterpret_cast<const f32x4*>(
            &prep[PRE_FRAG(bp * 8 + t + 1, mt, nt0 + n) + lane * 4]));
    }

    // ---- h[cur] @ W_hh^T (hi + lo split) ----
    #pragma unroll
    for (int s = 0; s < 16; ++s) {
      int u0 = s * 4 + a5;
      int ia = l15 * E_DIM + ((u0 ^ swz(l15)) << 3);
      bf16x8 H = *reinterpret_cast<const bf16x8*>(&h_hi[cur][ia]);
      bf16x8 L = *reinterpret_cast<const bf16x8*>(&h_lo[cur][ia]);
      #pragma unroll
      for (int n = 0; n < 4; ++n) {
        bf16x8 Bf = *reinterpret_cast<const bf16x8*>(wpH + n * 8192 + s * 512);
        acc[n] = __builtin_amdgcn_mfma_f32_16x16x32_bf16(H, Bf, acc[n], 0, 0, 0);
        acc[n] = __builtin_amdgcn_mfma_f32_16x16x32_bf16(L, Bf, acc[n], 0, 0, 0);
      }
    }

    if (t == KSIZE - 1) {
      #pragma unroll
      for (int n = 0; n < 4; ++n) {
        int ncol = (nt0 + n) * 16 + l15;
        #pragma unroll
        for (int r = 0; r < 4; ++r) {
          int row = a5 * 4 + r;
          out[(size_t)(w0 + row) * E_DIM + ncol] = tanh_fast(acc[n][r]);
        }
      }
    } else {
      // write h[cur^1]; other waves may still read h[cur] -- different buffer
      int nb = cur ^ 1;
      #pragma unroll
      for (int n = 0; n < 4; ++n) {
        int ncol = (nt0 + n) * 16 + l15;
        int ub = ncol >> 3, co = ncol & 7;
        #pragma unroll
        for (int r = 0; r < 4; ++r) {
          int row = a5 * 4 + r;
          float th = tanh_fast(acc[n][r]);
          unsigned short hi = f2bf(th);
          unsigned short lo = f2bf(th - bf2f(hi));
          int idx = row * E_DIM + ((ub ^ swz(row)) << 3) + co;
          h_hi[nb][idx] = hi;
          h_lo[nb][idx] = lo;
        }
      }
      __syncthreads();   // one barrier per step: h[nb] now visible to all
      cur = nb;
    }
  }
}

// ---------------------------------------------------------------------------
// Fallback (fused) for small ws_size.
// ---------------------------------------------------------------------------
__global__ __launch_bounds__(512, 1)
void rnnpool_fused(const float* __restrict__ x,
                   const unsigned short* __restrict__ wpack,
                   const float* __restrict__ bias,
                   float* __restrict__ out) {
  __shared__ unsigned short x_lds[R_WIN * E_DIM];
  __shared__ unsigned short h_hi[R_WIN * E_DIM];
  __shared__ unsigned short h_lo[R_WIN * E_DIM];

  const int tid  = threadIdx.x;
  const int lane = tid & 63;
  const int wid  = tid >> 6;
  const int w0   = blockIdx.x * R_WIN;
  const int l15 = lane & 15;
  const int a5  = lane >> 4;
  const int nt0 = wid * 4;

  float bias_r[4];
  #pragma unroll
  for (int n = 0; n < 4; ++n) bias_r[n] = bias[(nt0 + n) * 16 + l15];

  const unsigned short* wpI = wpack + nt0 * 8192 + lane * 8;
  const unsigned short* wpH = wpI + 262144;
  const int srow = tid >> 4;
  const int sc4  = tid & 15;

  for (int t = 0; t < KSIZE; ++t) {
    {
      const fv4* src4 = reinterpret_cast<const fv4*>(
          x + (size_t)((w0 + srow) * KSIZE + t) * E_DIM);
      #pragma unroll
      for (int j = 0; j < 8; ++j) {
        fv4 v = src4[sc4 + 16 * j];
        int col  = (sc4 + 16 * j) * 4;
        int idx  = srow * E_DIM + (((col >> 3) ^ swz(srow)) << 3) + (col & 7);
        u16x4 u;
        u[0] = f2bf(v.x); u[1] = f2bf(v.y); u[2] = f2bf(v.z); u[3] = f2bf(v.w);
        *reinterpret_cast<u16x4*>(&x_lds[idx]) = u;
      }
    }
    __syncthreads();

    f32x4 acc[2][4];
    #pragma unroll
    for (int mt = 0; mt < 2; ++mt)
      #pragma unroll
      for (int n = 0; n < 4; ++n) acc[mt][n] = (f32x4){0.f, 0.f, 0.f, 0.f};

    #pragma unroll
    for (int s = 0; s < 16; ++s) {
      int u0 = s * 4 + a5;
      int ia = l15 * E_DIM + ((u0 ^ swz(l15)) << 3);
      bf16x8 A0 = *reinterpret_cast<const bf16x8*>(&x_lds[ia]);
      bf16x8 A1 = *reinterpret_cast<const bf16x8*>(&x_lds[ia + 16 * E_DIM]);
      #pragma unroll
      for (int n = 0; n < 4; ++n) {
        bf16x8 Bf = *reinterpret_cast<const bf16x8*>(wpI + n * 8192 + s * 512);
        acc[0][n] = __builtin_amdgcn_mfma_f32_16x16x32_bf16(A0, Bf, acc[0][n], 0, 0, 0);
        acc[1][n] = __builtin_amdgcn_mfma_f32_16x16x32_bf16(A1, Bf, acc[1][n], 0, 0, 0);
      }
    }

    if (t > 0) {
      #pragma unroll
      for (int s = 0; s < 16; ++s) {
        int u0 = s * 4 + a5;
        int ia = l15 * E_DIM + ((u0 ^ swz(l15)) << 3);
        bf16x8 H0 = *reinterpret_cast<const bf16x8*>(&h_hi[ia]);
        bf16x8 H1 = *reinterpret_cast<const bf16x8*>(&h_hi[ia + 16 * E_DIM]);
        bf16x8 L0 = *reinterpret_cast<const bf16x8*>(&h_lo[ia]);
        bf16x8 L1 = *reinterpret_cast<const bf16x8*>(&h_lo[ia + 16 * E_DIM]);
        #pragma unroll
        for (int n = 0; n < 4; ++n) {
          bf16x8 Bf = *reinterpret_cast<const bf16x8*>(wpH + n * 8192 + s * 512);
          acc[0][n] = __builtin_amdgcn_mfma_f32_16x16x32_bf16(H0, Bf, acc[0][n], 0, 0, 0);
          acc[1][n] = __builtin_amdgcn_mfma_f32_16x16x32_bf16(H1, Bf, acc[1][n], 0, 0, 0);
          acc[0][n] = __builtin_amdgcn_mfma_f32_16x16x32_bf16(L0, Bf, acc[0][n], 0, 0, 0);
          acc[1][n] = __builtin_amdgcn_mfma_f32_16x16x32_bf16(L1, Bf, acc[1][n], 0, 0, 0);
        }
      }
    }
    __syncthreads();

    if (t == KSIZE - 1) {
      #pragma unroll
      for (int mt = 0; mt < 2; ++mt)
        #pragma unroll
        for (int n = 0; n < 4; ++n) {
          int ncol = (nt0 + n) * 16 + l15;
          #pragma unroll
          for (int r = 0; r < 4; ++r) {
            int row = mt * 16 + a5 * 4 + r;
            out[(size_t)(w0 + row) * E_DIM + ncol] = tanh_fast(acc[mt][n][r] + bias_r[n]);
          }
        }
    } else {
      #pragma unroll
      for (int mt = 0; mt < 2; ++mt)
        #pragma unroll
        for (int n = 0; n < 4; ++n) {
          int ncol = (nt0 + n) * 16 + l15;
          int ub = ncol >> 3, co = ncol & 7;
          #pragma unroll
          for (int r = 0; r < 4; ++r) {
            int row = mt * 16 + a5 * 4 + r;
            float th = tanh_fast(acc[mt][n][r] + bias_r[n]);
            unsigned short hi = f2bf(th);
            unsigned short lo = f2bf(th - bf2f(hi));
            int idx = row * E_DIM + ((ub ^ swz(row)) << 3) + co;
            h_hi[idx] = hi;
            h_lo[idx] = lo;
          }
        }
    }
  }
}

extern "C" void kernel_launch(void* const* d_in, const int* in_sizes, int n_in,
                              void* d_out, int out_size, void* d_ws, size_t ws_size,
                              hipStream_t stream) {
  const float* x   = (const float*)d_in[0];
  const float* Wih = (const float*)d_in[1];
  const float* Whh = (const float*)d_in[2];
  const float* bih = (const float*)d_in[3];
  const float* bhh = (const float*)d_in[4];
  float* out = (float*)d_out;

  const size_t PRE_BYTES  = (size_t)33554432 * 4;      // 134.2 MB
  const size_t WPK_BYTES  = (size_t)524288 * 2;        // 1 MB
  const size_t NEED       = PRE_BYTES + WPK_BYTES + 4096;

  if (ws_size >= NEED) {
    float*          prep  = (float*)d_ws;
    unsigned short* wpack = (unsigned short*)((char*)d_ws + PRE_BYTES);
    float*          bias  = (float*)((char*)d_ws + PRE_BYTES + WPK_BYTES);
    pack_kernel<<<256, 256, 0, stream>>>(Wih, Whh, bih, bhh, wpack, bias);
    pre_kernel<<<2048, 512, 0, stream>>>(x, wpack, bias, prep);
    rec_kernel<<<512, 512, 0, stream>>>(prep, wpack, out);
  } else {
    unsigned short* wpack = (unsigned short*)d_ws;
    float*          bias  = (float*)((char*)d_ws + WPK_BYTES);
    pack_kernel<<<256, 256, 0, stream>>>(Wih, Whh, bih, bhh, wpack, bias);
    rnnpool_fused<<<NBLK, 512, 0, stream>>>(x, wpack, bias, out);
  }
}

// Round 6
// 264.074 us; speedup vs baseline: 1.6398x; 1.6398x over previous
//
#include <hip/hip_runtime.h>
#include <hip/hip_bf16.h>
#include <stdint.h>

// RNNPool on MI355X: B=16, S=4096, E=512, window=8.
// Round 6: r4 grid shape (256 blocks, M=32 windows -- minimal weight traffic),
// with the latency fixes: explicit weight double-buffer software pipeline
// (forces VGPR headroom; r4/r5 compiled to 64 VGPR = zero load pipelining),
// h ping-pong in LDS (one barrier/step), PRE register prefetch.

#define E_DIM 512
#define KSIZE 8
#define R_WIN 32           // windows per block
#define NBLK  256

typedef __attribute__((ext_vector_type(8))) short          bf16x8;  // MFMA A/B frag
typedef __attribute__((ext_vector_type(4))) float          f32x4;   // MFMA C/D frag
typedef __attribute__((ext_vector_type(4))) float          fv4;
typedef __attribute__((ext_vector_type(4))) unsigned short u16x4;
typedef __attribute__((ext_vector_type(8))) unsigned short u16x8;

__device__ __forceinline__ unsigned short f2bf(float f) {
  union { float f; uint32_t u; } v; v.f = f;
  uint32_t u = v.u;
  uint32_t r = u + 0x7FFFu + ((u >> 16) & 1u);   // round-to-nearest-even
  return (unsigned short)(r >> 16);
}
__device__ __forceinline__ float bf2f(unsigned short h) {
  union { uint32_t u; float f; } v; v.u = ((uint32_t)h) << 16;
  return v.f;
}
__device__ __forceinline__ float tanh_fast(float v) {
  return 1.0f - 2.0f / (1.0f + __expf(2.0f * v));   // exact saturation, 1 v_exp
}
// LDS XOR-swizzle key (function of row only: write/read sides agree).
__device__ __forceinline__ int swz(int row) { return (row ^ (row >> 1)) & 7; }

// ---------------------------------------------------------------------------
// Pack W_ih / W_hh into bf16 fragment-major (mfma_f32_16x16x32_bf16 B-operand):
//   lane l holds W[n*16 + (l&15)][s*32 + (l>>4)*8 + j], ushort idx ((m*32+n)*16+s)*512 + l*8
// bias[n] = b_ih[n] + b_hh[n].
// ---------------------------------------------------------------------------
__global__ void pack_kernel(const float* __restrict__ Wih, const float* __restrict__ Whh,
                            const float* __restrict__ bih, const float* __restrict__ bhh,
                            unsigned short* __restrict__ wpack, float* __restrict__ bias) {
  int tid = blockIdx.x * 256 + threadIdx.x;          // 65536 threads total
  int l = tid & 63;
  int s = (tid >> 6) & 15;
  int n = (tid >> 10) & 31;
  int m = tid >> 15;
  const float* W = m ? Whh : Wih;
  int row = n * 16 + (l & 15);
  int k0  = s * 32 + (l >> 4) * 8;
  const float* src = W + row * E_DIM + k0;
  u16x8 u;
  #pragma unroll
  for (int j = 0; j < 8; ++j) u[j] = f2bf(src[j]);
  *reinterpret_cast<u16x8*>(wpack + (size_t)tid * 8) = u;
  if (tid < E_DIM) bias[tid] = bih[tid] + bhh[tid];
}

// PRE fragment layout: frag id = ((bt*2 + mt)*32 + nt), bt = b*8+t, b in [0,256)
// frag = 256 floats = 64 lanes x f32x4 (C/D: col=lane&15, row=(lane>>4)*4+r).
#define PRE_FRAG(bt, mt, nt) ((((size_t)(bt) * 2 + (mt)) * 32 + (nt)) * 256)

// ---------------------------------------------------------------------------
// Phase 1: PRE = x_t @ W_ih^T + bias. Grid 2048, 512 thr (8 waves x 4 N-tiles).
// x loads and PRE stores nontemporal so W_ih stays L2-resident.
// ---------------------------------------------------------------------------
__global__ __launch_bounds__(512, 4)
void pre_kernel(const float* __restrict__ x,
                const unsigned short* __restrict__ wpack,
                const float* __restrict__ bias,
                float* __restrict__ prep) {
  __shared__ unsigned short x_lds[R_WIN * E_DIM];   // 32 KB

  const int bt   = blockIdx.x;
  const int b    = bt >> 3;
  const int t    = bt & 7;
  const int w0   = b * R_WIN;
  const int tid  = threadIdx.x;
  const int lane = tid & 63;
  const int wid  = tid >> 6;          // 0..7
  const int l15  = lane & 15;
  const int a5   = lane >> 4;
  const int nt0  = wid * 4;

  float bias_r[4];
  #pragma unroll
  for (int n = 0; n < 4; ++n) bias_r[n] = bias[(nt0 + n) * 16 + l15];

  const unsigned short* wpI = wpack + nt0 * 8192 + lane * 8;

  // stage x (nontemporal: read-once stream; don't evict W_ih from L2)
  {
    const int srow = tid >> 4;
    const int sc4  = tid & 15;
    const fv4* src4 = reinterpret_cast<const fv4*>(
        x + (size_t)((w0 + srow) * KSIZE + t) * E_DIM);
    #pragma unroll
    for (int j = 0; j < 8; ++j) {
      fv4 v = __builtin_nontemporal_load(&src4[sc4 + 16 * j]);
      int col  = (sc4 + 16 * j) * 4;
      int idx  = srow * E_DIM + (((col >> 3) ^ swz(srow)) << 3) + (col & 7);
      u16x4 u;
      u[0] = f2bf(v.x); u[1] = f2bf(v.y); u[2] = f2bf(v.z); u[3] = f2bf(v.w);
      *reinterpret_cast<u16x4*>(&x_lds[idx]) = u;
    }
  }
  __syncthreads();

  f32x4 acc[2][4];
  #pragma unroll
  for (int mt = 0; mt < 2; ++mt)
    #pragma unroll
    for (int n = 0; n < 4; ++n) acc[mt][n] = (f32x4){0.f, 0.f, 0.f, 0.f};

  #pragma unroll
  for (int s = 0; s < 16; ++s) {
    int u0 = s * 4 + a5;
    int ia = l15 * E_DIM + ((u0 ^ swz(l15)) << 3);
    bf16x8 A0 = *reinterpret_cast<const bf16x8*>(&x_lds[ia]);
    bf16x8 A1 = *reinterpret_cast<const bf16x8*>(&x_lds[ia + 16 * E_DIM]);
    #pragma unroll
    for (int n = 0; n < 4; ++n) {
      bf16x8 Bf = *reinterpret_cast<const bf16x8*>(wpI + n * 8192 + s * 512);
      acc[0][n] = __builtin_amdgcn_mfma_f32_16x16x32_bf16(A0, Bf, acc[0][n], 0, 0, 0);
      acc[1][n] = __builtin_amdgcn_mfma_f32_16x16x32_bf16(A1, Bf, acc[1][n], 0, 0, 0);
    }
  }

  // store fragment-major, nontemporal (streams straight out, keeps L2 clean)
  #pragma unroll
  for (int mt = 0; mt < 2; ++mt)
    #pragma unroll
    for (int n = 0; n < 4; ++n) {
      f32x4 v = acc[mt][n];
      #pragma unroll
      for (int r = 0; r < 4; ++r) v[r] += bias_r[n];
      __builtin_nontemporal_store(v,
          reinterpret_cast<f32x4*>(&prep[PRE_FRAG(bt, mt, nt0 + n) + lane * 4]));
    }
}

// ---------------------------------------------------------------------------
// Phase 2: recurrence. Grid 256 (1 block/CU), 1024 thr = 16 waves x 2 N-tiles,
// M=32 windows. h ping-pong in LDS (bf16 hi+lo) -> one barrier per step.
// Weight B-frags stream from L2 through an explicit 2-deep register pipeline.
// ---------------------------------------------------------------------------
__global__ __launch_bounds__(1024, 4)
void rec_kernel(const float* __restrict__ prep,
                const unsigned short* __restrict__ wpack,
                float* __restrict__ out) {
  __shared__ unsigned short h_hi[2][R_WIN * E_DIM];   // 2 x 32 KB
  __shared__ unsigned short h_lo[2][R_WIN * E_DIM];   // 2 x 32 KB

  const int b    = blockIdx.x;
  const int w0   = b * R_WIN;
  const int tid  = threadIdx.x;
  const int lane = tid & 63;
  const int wid  = tid >> 6;            // 0..15
  const int l15  = lane & 15;
  const int a5   = lane >> 4;
  const int nt0  = wid * 2;

  const unsigned short* wpH = wpack + 262144 + nt0 * 8192 + lane * 8;

  // ---- t = 0: h[0] = tanh(PRE_0) ----
  #pragma unroll
  for (int mt = 0; mt < 2; ++mt)
    #pragma unroll
    for (int n = 0; n < 2; ++n) {
      f32x4 p = __builtin_nontemporal_load(reinterpret_cast<const f32x4*>(
          &prep[PRE_FRAG(b * 8 + 0, mt, nt0 + n) + lane * 4]));
      int ncol = (nt0 + n) * 16 + l15;
      int ub = ncol >> 3, co = ncol & 7;
      #pragma unroll
      for (int r = 0; r < 4; ++r) {
        int row = mt * 16 + a5 * 4 + r;
        float th = tanh_fast(p[r]);
        unsigned short hi = f2bf(th);
        unsigned short lo = f2bf(th - bf2f(hi));
        int idx = row * E_DIM + ((ub ^ swz(row)) << 3) + co;
        h_hi[0][idx] = hi;
        h_lo[0][idx] = lo;
      }
    }

  // prefetch PRE_1 into registers
  f32x4 nxt[2][2];
  #pragma unroll
  for (int mt = 0; mt < 2; ++mt)
    #pragma unroll
    for (int n = 0; n < 2; ++n)
      nxt[mt][n] = __builtin_nontemporal_load(reinterpret_cast<const f32x4*>(
          &prep[PRE_FRAG(b * 8 + 1, mt, nt0 + n) + lane * 4]));

  __syncthreads();   // h[0] visible

  int cur = 0;
  for (int t = 1; t < KSIZE; ++t) {
    f32x4 acc[2][2];
    #pragma unroll
    for (int mt = 0; mt < 2; ++mt)
      #pragma unroll
      for (int n = 0; n < 2; ++n) acc[mt][n] = nxt[mt][n];

    // issue next step's PRE loads now: latency hides under the MFMA phase
    if (t + 1 < KSIZE) {
      #pragma unroll
      for (int mt = 0; mt < 2; ++mt)
        #pragma unroll
        for (int n = 0; n < 2; ++n)
          nxt[mt][n] = __builtin_nontemporal_load(reinterpret_cast<const f32x4*>(
              &prep[PRE_FRAG(b * 8 + t + 1, mt, nt0 + n) + lane * 4]));
    }

    // ---- h[cur] @ W_hh^T with 2-deep weight register pipeline ----
    // wf[parity][n]: s-loop fully unrolled -> all indices compile-time (no scratch).
    bf16x8 wf[2][2];
    wf[0][0] = *reinterpret_cast<const bf16x8*>(wpH + 0 * 8192 + 0 * 512);
    wf[0][1] = *reinterpret_cast<const bf16x8*>(wpH + 1 * 8192 + 0 * 512);
    #pragma unroll
    for (int s = 0; s < 16; ++s) {
      const int pb = s & 1;
      if (s + 1 < 16) {   // prefetch next slice's weights before this slice's MFMAs
        wf[pb ^ 1][0] = *reinterpret_cast<const bf16x8*>(wpH + 0 * 8192 + (s + 1) * 512);
        wf[pb ^ 1][1] = *reinterpret_cast<const bf16x8*>(wpH + 1 * 8192 + (s + 1) * 512);
      }
      int u0 = s * 4 + a5;
      int ia = l15 * E_DIM + ((u0 ^ swz(l15)) << 3);
      bf16x8 H0 = *reinterpret_cast<const bf16x8*>(&h_hi[cur][ia]);
      bf16x8 H1 = *reinterpret_cast<const bf16x8*>(&h_hi[cur][ia + 16 * E_DIM]);
      bf16x8 L0 = *reinterpret_cast<const bf16x8*>(&h_lo[cur][ia]);
      bf16x8 L1 = *reinterpret_cast<const bf16x8*>(&h_lo[cur][ia + 16 * E_DIM]);
      #pragma unroll
      for (int n = 0; n < 2; ++n) {
        acc[0][n] = __builtin_amdgcn_mfma_f32_16x16x32_bf16(H0, wf[pb][n], acc[0][n], 0, 0, 0);
        acc[1][n] = __builtin_amdgcn_mfma_f32_16x16x32_bf16(H1, wf[pb][n], acc[1][n], 0, 0, 0);
        acc[0][n] = __builtin_amdgcn_mfma_f32_16x16x32_bf16(L0, wf[pb][n], acc[0][n], 0, 0, 0);
        acc[1][n] = __builtin_amdgcn_mfma_f32_16x16x32_bf16(L1, wf[pb][n], acc[1][n], 0, 0, 0);
      }
    }

    if (t == KSIZE - 1) {
      #pragma unroll
      for (int mt = 0; mt < 2; ++mt)
        #pragma unroll
        for (int n = 0; n < 2; ++n) {
          int ncol = (nt0 + n) * 16 + l15;
          #pragma unroll
          for (int r = 0; r < 4; ++r) {
            int row = mt * 16 + a5 * 4 + r;
            out[(size_t)(w0 + row) * E_DIM + ncol] = tanh_fast(acc[mt][n][r]);
          }
        }
    } else {
      // write h[cur^1]; other waves may still read h[cur] -- different buffer
      int nb = cur ^ 1;
      #pragma unroll
      for (int mt = 0; mt < 2; ++mt)
        #pragma unroll
        for (int n = 0; n < 2; ++n) {
          int ncol = (nt0 + n) * 16 + l15;
          int ub = ncol >> 3, co = ncol & 7;
          #pragma unroll
          for (int r = 0; r < 4; ++r) {
            int row = mt * 16 + a5 * 4 + r;
            float th = tanh_fast(acc[mt][n][r]);
            unsigned short hi = f2bf(th);
            unsigned short lo = f2bf(th - bf2f(hi));
            int idx = row * E_DIM + ((ub ^ swz(row)) << 3) + co;
            h_hi[nb][idx] = hi;
            h_lo[nb][idx] = lo;
          }
        }
      __syncthreads();   // one barrier per step: h[nb] visible to all
      cur = nb;
    }
  }
}

// ---------------------------------------------------------------------------
// Fallback (fused) for small ws_size.
// ---------------------------------------------------------------------------
__global__ __launch_bounds__(512, 1)
void rnnpool_fused(const float* __restrict__ x,
                   const unsigned short* __restrict__ wpack,
                   const float* __restrict__ bias,
                   float* __restrict__ out) {
  __shared__ unsigned short x_lds[R_WIN * E_DIM];
  __shared__ unsigned short h_hi[R_WIN * E_DIM];
  __shared__ unsigned short h_lo[R_WIN * E_DIM];

  const int tid  = threadIdx.x;
  const int lane = tid & 63;
  const int wid  = tid >> 6;
  const int w0   = blockIdx.x * R_WIN;
  const int l15 = lane & 15;
  const int a5  = lane >> 4;
  const int nt0 = wid * 4;

  float bias_r[4];
  #pragma unroll
  for (int n = 0; n < 4; ++n) bias_r[n] = bias[(nt0 + n) * 16 + l15];

  const unsigned short* wpI = wpack + nt0 * 8192 + lane * 8;
  const unsigned short* wpH = wpI + 262144;
  const int srow = tid >> 4;
  const int sc4  = tid & 15;

  for (int t = 0; t < KSIZE; ++t) {
    {
      const fv4* src4 = reinterpret_cast<const fv4*>(
          x + (size_t)((w0 + srow) * KSIZE + t) * E_DIM);
      #pragma unroll
      for (int j = 0; j < 8; ++j) {
        fv4 v = src4[sc4 + 16 * j];
        int col  = (sc4 + 16 * j) * 4;
        int idx  = srow * E_DIM + (((col >> 3) ^ swz(srow)) << 3) + (col & 7);
        u16x4 u;
        u[0] = f2bf(v.x); u[1] = f2bf(v.y); u[2] = f2bf(v.z); u[3] = f2bf(v.w);
        *reinterpret_cast<u16x4*>(&x_lds[idx]) = u;
      }
    }
    __syncthreads();

    f32x4 acc[2][4];
    #pragma unroll
    for (int mt = 0; mt < 2; ++mt)
      #pragma unroll
      for (int n = 0; n < 4; ++n) acc[mt][n] = (f32x4){0.f, 0.f, 0.f, 0.f};

    #pragma unroll
    for (int s = 0; s < 16; ++s) {
      int u0 = s * 4 + a5;
      int ia = l15 * E_DIM + ((u0 ^ swz(l15)) << 3);
      bf16x8 A0 = *reinterpret_cast<const bf16x8*>(&x_lds[ia]);
      bf16x8 A1 = *reinterpret_cast<const bf16x8*>(&x_lds[ia + 16 * E_DIM]);
      #pragma unroll
      for (int n = 0; n < 4; ++n) {
        bf16x8 Bf = *reinterpret_cast<const bf16x8*>(wpI + n * 8192 + s * 512);
        acc[0][n] = __builtin_amdgcn_mfma_f32_16x16x32_bf16(A0, Bf, acc[0][n], 0, 0, 0);
        acc[1][n] = __builtin_amdgcn_mfma_f32_16x16x32_bf16(A1, Bf, acc[1][n], 0, 0, 0);
      }
    }

    if (t > 0) {
      #pragma unroll
      for (int s = 0; s < 16; ++s) {
        int u0 = s * 4 + a5;
        int ia = l15 * E_DIM + ((u0 ^ swz(l15)) << 3);
        bf16x8 H0 = *reinterpret_cast<const bf16x8*>(&h_hi[ia]);
        bf16x8 H1 = *reinterpret_cast<const bf16x8*>(&h_hi[ia + 16 * E_DIM]);
        bf16x8 L0 = *reinterpret_cast<const bf16x8*>(&h_lo[ia]);
        bf16x8 L1 = *reinterpret_cast<const bf16x8*>(&h_lo[ia + 16 * E_DIM]);
        #pragma unroll
        for (int n = 0; n < 4; ++n) {
          bf16x8 Bf = *reinterpret_cast<const bf16x8*>(wpH + n * 8192 + s * 512);
          acc[0][n] = __builtin_amdgcn_mfma_f32_16x16x32_bf16(H0, Bf, acc[0][n], 0, 0, 0);
          acc[1][n] = __builtin_amdgcn_mfma_f32_16x16x32_bf16(H1, Bf, acc[1][n], 0, 0, 0);
          acc[0][n] = __builtin_amdgcn_mfma_f32_16x16x32_bf16(L0, Bf, acc[0][n], 0, 0, 0);
          acc[1][n] = __builtin_amdgcn_mfma_f32_16x16x32_bf16(L1, Bf, acc[1][n], 0, 0, 0);
        }
      }
    }
    __syncthreads();

    if (t == KSIZE - 1) {
      #pragma unroll
      for (int mt = 0; mt < 2; ++mt)
        #pragma unroll
        for (int n = 0; n < 4; ++n) {
          int ncol = (nt0 + n) * 16 + l15;
          #pragma unroll
          for (int r = 0; r < 4; ++r) {
            int row = mt * 16 + a5 * 4 + r;
            out[(size_t)(w0 + row) * E_DIM + ncol] = tanh_fast(acc[mt][n][r] + bias_r[n]);
          }
        }
    } else {
      #pragma unroll
      for (int mt = 0; mt < 2; ++mt)
        #pragma unroll
        for (int n = 0; n < 4; ++n) {
          int ncol = (nt0 + n) * 16 + l15;
          int ub = ncol >> 3, co = ncol & 7;
          #pragma unroll
          for (int r = 0; r < 4; ++r) {
            int row = mt * 16 + a5 * 4 + r;
            float th = tanh_fast(acc[mt][n][r] + bias_r[n]);
            unsigned short hi = f2bf(th);
            unsigned short lo = f2bf(th - bf2f(hi));
            int idx = row * E_DIM + ((ub ^ swz(row)) << 3) + co;
            h_hi[idx] = hi;
            h_lo[idx] = lo;
          }
        }
    }
  }
}

extern "C" void kernel_launch(void* const* d_in, const int* in_sizes, int n_in,
                              void* d_out, int out_size, void* d_ws, size_t ws_size,
                              hipStream_t stream) {
  const float* x   = (const float*)d_in[0];
  const float* Wih = (const float*)d_in[1];
  const float* Whh = (const float*)d_in[2];
  const float* bih = (const float*)d_in[3];
  const float* bhh = (const float*)d_in[4];
  float* out = (float*)d_out;

  const size_t PRE_BYTES  = (size_t)33554432 * 4;      // 134.2 MB
  const size_t WPK_BYTES  = (size_t)524288 * 2;        // 1 MB
  const size_t NEED       = PRE_BYTES + WPK_BYTES + 4096;

  if (ws_size >= NEED) {
    float*          prep  = (float*)d_ws;
    unsigned short* wpack = (unsigned short*)((char*)d_ws + PRE_BYTES);
    float*          bias  = (float*)((char*)d_ws + PRE_BYTES + WPK_BYTES);
    pack_kernel<<<256, 256, 0, stream>>>(Wih, Whh, bih, bhh, wpack, bias);
    pre_kernel<<<2048, 512, 0, stream>>>(x, wpack, bias, prep);
    rec_kernel<<<NBLK, 1024, 0, stream>>>(prep, wpack, out);
  } else {
    unsigned short* wpack = (unsigned short*)d_ws;
    float*          bias  = (float*)((char*)d_ws + WPK_BYTES);
    pack_kernel<<<256, 256, 0, stream>>>(Wih, Whh, bih, bhh, wpack, bias);
    rnnpool_fused<<<NBLK, 512, 0, stream>>>(x, wpack, bias, out);
  }
}